// Round 1
// baseline (1294.956 us; speedup 1.0000x reference)
//
#include <hip/hip_runtime.h>
#include <hip/hip_bf16.h>

typedef __attribute__((ext_vector_type(8))) short bf16x8;
typedef __attribute__((ext_vector_type(4))) float f32x4;

#define SEQ   8192
#define DEM   256
#define SCALE 0.0625f   // 1/sqrt(256)

static __device__ __forceinline__ unsigned short f2bf(float f) {
  union { float f; unsigned int u; } v; v.f = f;
  return (unsigned short)((v.u + 0x7fffu + ((v.u >> 16) & 1u)) >> 16);
}

// ---- projections: qb[s][d] = sum_e x[s][e] Wq[d][e]; kb likewise; vtb[d][s] = sum_e x[s][e] Wv[d][e]
__global__ __launch_bounds__(256) void proj_kernel(
    const float* __restrict__ x,  const float* __restrict__ Wq,
    const float* __restrict__ Wk, const float* __restrict__ Wv,
    unsigned short* __restrict__ qb, unsigned short* __restrict__ kb,
    unsigned short* __restrict__ vtb)
{
  const int m0 = blockIdx.x * 128;
  const int n0 = blockIdx.y * 128;
  const int which = blockIdx.z;
  const float* __restrict__ W = (which == 0) ? Wq : (which == 1) ? Wk : Wv;

  __shared__ unsigned short As[128 * 64];
  __shared__ unsigned short Bs[128 * 64];

  const int tid  = threadIdx.x;
  const int wave = tid >> 6, lane = tid & 63;
  const int wm = wave >> 1, wn = wave & 1;
  const int lr = lane & 15, lg = lane >> 4;

  f32x4 acc[4][4];
  #pragma unroll
  for (int i = 0; i < 4; i++)
    #pragma unroll
    for (int j = 0; j < 4; j++) acc[i][j] = (f32x4){0.f, 0.f, 0.f, 0.f};

  for (int k0 = 0; k0 < DEM; k0 += 64) {
    __syncthreads();
    #pragma unroll
    for (int p = 0; p < 8; p++) {
      int c   = p * 256 + tid;
      int row = c >> 4;
      int col = (c & 15) << 2;
      float4 fA = *reinterpret_cast<const float4*>(&x[(m0 + row) * DEM + k0 + col]);
      float4 fB = *reinterpret_cast<const float4*>(&W[(n0 + row) * DEM + k0 + col]);
      uint2 hA, hB;
      hA.x = f2bf(fA.x) | ((unsigned)f2bf(fA.y) << 16);
      hA.y = f2bf(fA.z) | ((unsigned)f2bf(fA.w) << 16);
      hB.x = f2bf(fB.x) | ((unsigned)f2bf(fB.y) << 16);
      hB.y = f2bf(fB.z) | ((unsigned)f2bf(fB.w) << 16);
      int byte = (row * 128 + (col << 1)) ^ ((row & 7) << 4);
      *reinterpret_cast<uint2*>(reinterpret_cast<char*>(As) + byte) = hA;
      *reinterpret_cast<uint2*>(reinterpret_cast<char*>(Bs) + byte) = hB;
    }
    __syncthreads();

    #pragma unroll
    for (int ks = 0; ks < 2; ks++) {
      bf16x8 a[4], b[4];
      #pragma unroll
      for (int mt = 0; mt < 4; mt++) {
        int row  = wm * 64 + mt * 16 + lr;
        int byte = (row * 128 + ks * 64 + lg * 16) ^ ((row & 7) << 4);
        a[mt] = *reinterpret_cast<const bf16x8*>(reinterpret_cast<const char*>(As) + byte);
      }
      #pragma unroll
      for (int nt = 0; nt < 4; nt++) {
        int row  = wn * 64 + nt * 16 + lr;
        int byte = (row * 128 + ks * 64 + lg * 16) ^ ((row & 7) << 4);
        b[nt] = *reinterpret_cast<const bf16x8*>(reinterpret_cast<const char*>(Bs) + byte);
      }
      #pragma unroll
      for (int mt = 0; mt < 4; mt++)
        #pragma unroll
        for (int nt = 0; nt < 4; nt++)
          acc[mt][nt] = __builtin_amdgcn_mfma_f32_16x16x32_bf16(a[mt], b[nt], acc[mt][nt], 0, 0, 0);
    }
  }

  #pragma unroll
  for (int mt = 0; mt < 4; mt++)
    #pragma unroll
    for (int nt = 0; nt < 4; nt++)
      #pragma unroll
      for (int r = 0; r < 4; r++) {
        int row = m0 + wm * 64 + mt * 16 + lg * 4 + r;
        int col = n0 + wn * 64 + nt * 16 + lr;
        unsigned short h = f2bf(acc[mt][nt][r]);
        if (which == 0)      qb[row * DEM + col]  = h;
        else if (which == 1) kb[row * DEM + col]  = h;
        else                 vtb[(size_t)col * SEQ + row] = h;
      }
}

// ---- causal flash attention: out[s][d], fp32
__global__ __launch_bounds__(128) void attn_kernel(
    const unsigned short* __restrict__ qb, const unsigned short* __restrict__ kb,
    const unsigned short* __restrict__ vtb, float* __restrict__ out)
{
  const int qtile = blockIdx.x;        // 32 q-rows per block
  const int q0 = qtile * 32;
  const int tid = threadIdx.x;
  const int wave = tid >> 6, lane = tid & 63;
  const int lr = lane & 15, lg = lane >> 4;
  const int qrow = q0 + wave * 16;     // this wave's 16 q-rows

  __shared__ unsigned short Ks[32 * 256];   // K tile, swizzled, 16KB
  __shared__ unsigned short Vs[256 * 32];   // Vt tile [d][kv], swizzled, 16KB
  __shared__ unsigned short Ps[2][16 * 32]; // per-wave P, swizzled, 1KB each

  // Q fragments held in registers for the whole kernel (A-operand: m=lr, k contiguous)
  bf16x8 qf[8];
  #pragma unroll
  for (int ks = 0; ks < 8; ks++)
    qf[ks] = *reinterpret_cast<const bf16x8*>(&qb[(qrow + lr) * DEM + ks * 32 + lg * 8]);

  f32x4 o[16];
  #pragma unroll
  for (int d = 0; d < 16; d++) o[d] = (f32x4){0.f, 0.f, 0.f, 0.f};
  float m_run[4], l_run[4];
  #pragma unroll
  for (int r = 0; r < 4; r++) { m_run[r] = -3.0e38f; l_run[r] = 0.f; }

  for (int t = 0; t <= qtile; t++) {
    const int kv0 = t * 32;
    __syncthreads();
    // stage K tile: 32 rows x 512B
    #pragma unroll
    for (int p = 0; p < 8; p++) {
      int c = p * 128 + tid;
      int row = c >> 5, cc = c & 31;
      uint4 v = *reinterpret_cast<const uint4*>(&kb[(kv0 + row) * DEM + cc * 8]);
      int byte = (row * 512 + cc * 16) ^ ((row & 7) << 4);
      *reinterpret_cast<uint4*>(reinterpret_cast<char*>(Ks) + byte) = v;
    }
    // stage Vt tile: 256 rows x 64B
    #pragma unroll
    for (int p = 0; p < 8; p++) {
      int c = p * 128 + tid;
      int row = c >> 2, cc = c & 3;
      uint4 v = *reinterpret_cast<const uint4*>(&vtb[(size_t)row * SEQ + kv0 + cc * 8]);
      int byte = (row * 64 + cc * 16) ^ ((row & 7) << 4);
      *reinterpret_cast<uint4*>(reinterpret_cast<char*>(Vs) + byte) = v;
    }
    __syncthreads();

    // scores: S = Q K^T (m=q local, n=kv local)
    f32x4 sc[2];
    sc[0] = (f32x4){0.f, 0.f, 0.f, 0.f};
    sc[1] = (f32x4){0.f, 0.f, 0.f, 0.f};
    #pragma unroll
    for (int ks = 0; ks < 8; ks++)
      #pragma unroll
      for (int nt = 0; nt < 2; nt++) {
        int krow = nt * 16 + lr;
        int byte = (krow * 512 + ks * 64 + lg * 16) ^ ((krow & 7) << 4);
        bf16x8 kf = *reinterpret_cast<const bf16x8*>(reinterpret_cast<const char*>(Ks) + byte);
        sc[nt] = __builtin_amdgcn_mfma_f32_16x16x32_bf16(qf[ks], kf, sc[nt], 0, 0, 0);
      }

    // online softmax (rows live in 16-lane groups; reg r -> q-row lg*4+r)
    const bool diag = (t == qtile);
    float p0[4], p1[4], corr[4];
    #pragma unroll
    for (int r = 0; r < 4; r++) {
      float s0 = sc[0][r] * SCALE;
      float s1 = sc[1][r] * SCALE;
      if (diag) {
        int i_glob = qrow + lg * 4 + r;
        if (kv0 + lr      > i_glob) s0 = -3.0e38f;
        if (kv0 + 16 + lr > i_glob) s1 = -3.0e38f;
      }
      p0[r] = s0; p1[r] = s1;
    }
    #pragma unroll
    for (int r = 0; r < 4; r++) {
      float mx = fmaxf(p0[r], p1[r]);
      mx = fmaxf(mx, __shfl_xor(mx, 1));
      mx = fmaxf(mx, __shfl_xor(mx, 2));
      mx = fmaxf(mx, __shfl_xor(mx, 4));
      mx = fmaxf(mx, __shfl_xor(mx, 8));
      float mnew = fmaxf(m_run[r], mx);
      float c = __expf(m_run[r] - mnew);
      m_run[r] = mnew;
      float e0 = __expf(p0[r] - mnew);
      float e1 = __expf(p1[r] - mnew);
      p0[r] = e0; p1[r] = e1;
      float sum = e0 + e1;
      sum += __shfl_xor(sum, 1);
      sum += __shfl_xor(sum, 2);
      sum += __shfl_xor(sum, 4);
      sum += __shfl_xor(sum, 8);
      l_run[r] = l_run[r] * c + sum;
      corr[r] = c;
    }
    // P (bf16) -> per-wave LDS to re-layout C-frag -> A-frag
    #pragma unroll
    for (int r = 0; r < 4; r++) {
      int row = lg * 4 + r;
      int b0 = (row * 64 + lr * 2)        ^ ((row & 7) << 4);
      int b1 = (row * 64 + (16 + lr) * 2) ^ ((row & 7) << 4);
      *reinterpret_cast<unsigned short*>(reinterpret_cast<char*>(Ps[wave]) + b0) = f2bf(p0[r]);
      *reinterpret_cast<unsigned short*>(reinterpret_cast<char*>(Ps[wave]) + b1) = f2bf(p1[r]);
    }
    // rescale O
    #pragma unroll
    for (int d = 0; d < 16; d++)
      #pragma unroll
      for (int r = 0; r < 4; r++) o[d][r] *= corr[r];
    // PV: o[q][d] += P[q][kv] * Vt[d][kv]
    {
      int pbyte = (lr * 64 + lg * 16) ^ ((lr & 7) << 4);
      bf16x8 pf = *reinterpret_cast<const bf16x8*>(reinterpret_cast<const char*>(Ps[wave]) + pbyte);
      #pragma unroll
      for (int d = 0; d < 16; d++) {
        int vrow  = d * 16 + lr;
        int vbyte = (vrow * 64 + lg * 16) ^ ((vrow & 7) << 4);
        bf16x8 vf = *reinterpret_cast<const bf16x8*>(reinterpret_cast<const char*>(Vs) + vbyte);
        o[d] = __builtin_amdgcn_mfma_f32_16x16x32_bf16(pf, vf, o[d], 0, 0, 0);
      }
    }
  }

  #pragma unroll
  for (int d = 0; d < 16; d++)
    #pragma unroll
    for (int r = 0; r < 4; r++) {
      int row = qrow + lg * 4 + r;
      int col = d * 16 + lr;
      out[row * DEM + col] = o[d][r] / l_run[r];
    }
}

extern "C" void kernel_launch(void* const* d_in, const int* in_sizes, int n_in,
                              void* d_out, int out_size, void* d_ws, size_t ws_size,
                              hipStream_t stream)
{
  const float* x  = (const float*)d_in[0];
  const float* Wq = (const float*)d_in[1];
  const float* Wk = (const float*)d_in[2];
  const float* Wv = (const float*)d_in[3];
  unsigned short* qb  = (unsigned short*)d_ws;
  unsigned short* kb  = qb + (size_t)SEQ * DEM;
  unsigned short* vtb = kb + (size_t)SEQ * DEM;
  proj_kernel<<<dim3(64, 2, 3), 256, 0, stream>>>(x, Wq, Wk, Wv, qb, kb, vtb);
  attn_kernel<<<dim3(256), 128, 0, stream>>>(qb, kb, vtb, (float*)d_out);
}

// Round 2
// 501.328 us; speedup vs baseline: 2.5831x; 2.5831x over previous
//
#include <hip/hip_runtime.h>
#include <hip/hip_bf16.h>

typedef __attribute__((ext_vector_type(8))) short bf16x8;
typedef __attribute__((ext_vector_type(4))) float f32x4;

#define SEQ   8192
#define DEM   256
#define SCALE 0.0625f   // 1/sqrt(256)
#define CHUNK 1024
#define NTASKS 576      // sum over 128 qtiles of ceil((q+1)*64/1024)

static __device__ __forceinline__ unsigned short f2bf(float f) {
  union { float f; unsigned int u; } v; v.f = f;
  return (unsigned short)((v.u + 0x7fffu + ((v.u >> 16) & 1u)) >> 16);
}

// ---- projections: qb[s][d] = sum_e x[s][e] Wq[d][e]; kb likewise; vtb[d][s] = sum_e x[s][e] Wv[d][e]
__global__ __launch_bounds__(256) void proj_kernel(
    const float* __restrict__ x,  const float* __restrict__ Wq,
    const float* __restrict__ Wk, const float* __restrict__ Wv,
    unsigned short* __restrict__ qb, unsigned short* __restrict__ kb,
    unsigned short* __restrict__ vtb)
{
  const int m0 = blockIdx.x * 128;
  const int n0 = blockIdx.y * 128;
  const int which = blockIdx.z;
  const float* __restrict__ W = (which == 0) ? Wq : (which == 1) ? Wk : Wv;

  __shared__ unsigned short As[128 * 64];
  __shared__ unsigned short Bs[128 * 64];

  const int tid  = threadIdx.x;
  const int wave = tid >> 6, lane = tid & 63;
  const int wm = wave >> 1, wn = wave & 1;
  const int lr = lane & 15, lg = lane >> 4;

  f32x4 acc[4][4];
  #pragma unroll
  for (int i = 0; i < 4; i++)
    #pragma unroll
    for (int j = 0; j < 4; j++) acc[i][j] = (f32x4){0.f, 0.f, 0.f, 0.f};

  for (int k0 = 0; k0 < DEM; k0 += 64) {
    __syncthreads();
    #pragma unroll
    for (int p = 0; p < 8; p++) {
      int c   = p * 256 + tid;
      int row = c >> 4;
      int col = (c & 15) << 2;
      float4 fA = *reinterpret_cast<const float4*>(&x[(m0 + row) * DEM + k0 + col]);
      float4 fB = *reinterpret_cast<const float4*>(&W[(n0 + row) * DEM + k0 + col]);
      uint2 hA, hB;
      hA.x = f2bf(fA.x) | ((unsigned)f2bf(fA.y) << 16);
      hA.y = f2bf(fA.z) | ((unsigned)f2bf(fA.w) << 16);
      hB.x = f2bf(fB.x) | ((unsigned)f2bf(fB.y) << 16);
      hB.y = f2bf(fB.z) | ((unsigned)f2bf(fB.w) << 16);
      int byte = (row * 128 + (col << 1)) ^ ((row & 7) << 4);
      *reinterpret_cast<uint2*>(reinterpret_cast<char*>(As) + byte) = hA;
      *reinterpret_cast<uint2*>(reinterpret_cast<char*>(Bs) + byte) = hB;
    }
    __syncthreads();

    #pragma unroll
    for (int ks = 0; ks < 2; ks++) {
      bf16x8 a[4], b[4];
      #pragma unroll
      for (int mt = 0; mt < 4; mt++) {
        int row  = wm * 64 + mt * 16 + lr;
        int byte = (row * 128 + ks * 64 + lg * 16) ^ ((row & 7) << 4);
        a[mt] = *reinterpret_cast<const bf16x8*>(reinterpret_cast<const char*>(As) + byte);
      }
      #pragma unroll
      for (int nt = 0; nt < 4; nt++) {
        int row  = wn * 64 + nt * 16 + lr;
        int byte = (row * 128 + ks * 64 + lg * 16) ^ ((row & 7) << 4);
        b[nt] = *reinterpret_cast<const bf16x8*>(reinterpret_cast<const char*>(Bs) + byte);
      }
      #pragma unroll
      for (int mt = 0; mt < 4; mt++)
        #pragma unroll
        for (int nt = 0; nt < 4; nt++)
          acc[mt][nt] = __builtin_amdgcn_mfma_f32_16x16x32_bf16(a[mt], b[nt], acc[mt][nt], 0, 0, 0);
    }
  }

  #pragma unroll
  for (int mt = 0; mt < 4; mt++)
    #pragma unroll
    for (int nt = 0; nt < 4; nt++)
      #pragma unroll
      for (int r = 0; r < 4; r++) {
        int row = m0 + wm * 64 + mt * 16 + lg * 4 + r;
        int col = n0 + wn * 64 + nt * 16 + lr;
        unsigned short h = f2bf(acc[mt][nt][r]);
        if (which == 0)      qb[row * DEM + col]  = h;
        else if (which == 1) kb[row * DEM + col]  = h;
        else                 vtb[(size_t)col * SEQ + row] = h;
      }
}

// ---- attention tasks: block = (qtile of 64 rows, kv chunk of <=1024). 4 waves, 16 q-rows each.
// No __syncthreads in the main loop; K/V fragments read directly from global (L1/L2-hot).
// Writes unnormalized partial O + per-row (m, l) to workspace.
__global__ __launch_bounds__(256, 2) void attn_kernel(
    const unsigned short* __restrict__ qb, const unsigned short* __restrict__ kb,
    const unsigned short* __restrict__ vtb,
    float* __restrict__ pO, float* __restrict__ ml)
{
  const int t = blockIdx.x;
  // map task -> (qtile q, chunk c): nch(q) = (q>>4)+1
  int q = 0, s = 0;
  for (;;) { int n = (q >> 4) + 1; if (t < s + n) break; s += n; ++q; }
  const int c = t - s;
  const int kv_lo = c * CHUNK;
  const int kv_hi = min((q + 1) * 64, kv_lo + CHUNK);

  const int tid = threadIdx.x;
  const int wave = tid >> 6, lane = tid & 63;
  const int lr = lane & 15, lg = lane >> 4;
  const int qrow = q * 64 + wave * 16;          // this wave's 16 q-rows
  // last kv tile this wave needs (causal): smallest multiple of 64 >= qrow+16
  const int kv_hi_w = min(kv_hi, (qrow + 16 + 63) & ~63);

  __shared__ unsigned short Ps[4][16 * 64];     // per-wave P transpose buffer, swizzled

  bf16x8 qf[8];
  #pragma unroll
  for (int ks = 0; ks < 8; ks++)
    qf[ks] = *reinterpret_cast<const bf16x8*>(&qb[(size_t)(qrow + lr) * DEM + ks * 32 + lg * 8]);

  f32x4 o[16];
  #pragma unroll
  for (int d = 0; d < 16; d++) o[d] = (f32x4){0.f, 0.f, 0.f, 0.f};
  float m_run[4], l_run[4];
  #pragma unroll
  for (int r = 0; r < 4; r++) { m_run[r] = -3.0e38f; l_run[r] = 0.f; }

  for (int kv0 = kv_lo; kv0 < kv_hi_w; kv0 += 64) {
    // ---- QK^T over a 64-kv tile
    f32x4 sc[4];
    #pragma unroll
    for (int nt = 0; nt < 4; nt++) sc[nt] = (f32x4){0.f, 0.f, 0.f, 0.f};
    const unsigned short* kp = kb + (size_t)(kv0 + lr) * DEM + lg * 8;
    #pragma unroll
    for (int ks = 0; ks < 8; ks++) {
      bf16x8 k0 = *reinterpret_cast<const bf16x8*>(kp + ks * 32);
      bf16x8 k1 = *reinterpret_cast<const bf16x8*>(kp + 16 * DEM + ks * 32);
      bf16x8 k2 = *reinterpret_cast<const bf16x8*>(kp + 32 * DEM + ks * 32);
      bf16x8 k3 = *reinterpret_cast<const bf16x8*>(kp + 48 * DEM + ks * 32);
      sc[0] = __builtin_amdgcn_mfma_f32_16x16x32_bf16(qf[ks], k0, sc[0], 0, 0, 0);
      sc[1] = __builtin_amdgcn_mfma_f32_16x16x32_bf16(qf[ks], k1, sc[1], 0, 0, 0);
      sc[2] = __builtin_amdgcn_mfma_f32_16x16x32_bf16(qf[ks], k2, sc[2], 0, 0, 0);
      sc[3] = __builtin_amdgcn_mfma_f32_16x16x32_bf16(qf[ks], k3, sc[3], 0, 0, 0);
    }

    // ---- online softmax (row r lives in 16-lane group; q-row = qrow + lg*4 + r)
    const bool diag = (kv0 + 63 > qrow);
    float corr[4];
    char* pbase = reinterpret_cast<char*>(Ps[wave]);
    #pragma unroll
    for (int r = 0; r < 4; r++) {
      const int row_g = qrow + lg * 4 + r;
      float sm0 = sc[0][r] * SCALE, sm1 = sc[1][r] * SCALE;
      float sm2 = sc[2][r] * SCALE, sm3 = sc[3][r] * SCALE;
      if (diag) {
        if (kv0 +      lr > row_g) sm0 = -3.0e38f;
        if (kv0 + 16 + lr > row_g) sm1 = -3.0e38f;
        if (kv0 + 32 + lr > row_g) sm2 = -3.0e38f;
        if (kv0 + 48 + lr > row_g) sm3 = -3.0e38f;
      }
      float mx = fmaxf(fmaxf(sm0, sm1), fmaxf(sm2, sm3));
      mx = fmaxf(mx, __shfl_xor(mx, 1));
      mx = fmaxf(mx, __shfl_xor(mx, 2));
      mx = fmaxf(mx, __shfl_xor(mx, 4));
      mx = fmaxf(mx, __shfl_xor(mx, 8));
      const float mnew = fmaxf(m_run[r], mx);
      const float cr = __expf(m_run[r] - mnew);
      const float e0 = __expf(sm0 - mnew), e1 = __expf(sm1 - mnew);
      const float e2 = __expf(sm2 - mnew), e3 = __expf(sm3 - mnew);
      float sum = (e0 + e1) + (e2 + e3);
      sum += __shfl_xor(sum, 1);
      sum += __shfl_xor(sum, 2);
      sum += __shfl_xor(sum, 4);
      sum += __shfl_xor(sum, 8);
      m_run[r] = mnew;
      l_run[r] = l_run[r] * cr + sum;
      corr[r] = cr;
      const int prow = lg * 4 + r;
      const int swz = (prow & 7) << 4;
      *reinterpret_cast<unsigned short*>(pbase + ((prow * 128 + lr * 2)        ^ swz)) = f2bf(e0);
      *reinterpret_cast<unsigned short*>(pbase + ((prow * 128 + 32 + lr * 2)   ^ swz)) = f2bf(e1);
      *reinterpret_cast<unsigned short*>(pbase + ((prow * 128 + 64 + lr * 2)   ^ swz)) = f2bf(e2);
      *reinterpret_cast<unsigned short*>(pbase + ((prow * 128 + 96 + lr * 2)   ^ swz)) = f2bf(e3);
    }

    // ---- rescale O
    #pragma unroll
    for (int d = 0; d < 16; d++)
      #pragma unroll
      for (int r = 0; r < 4; r++) o[d][r] *= corr[r];

    // ---- PV: o[q][dcol] += P[q][kv] * Vt[dcol][kv]
    bf16x8 pf0, pf1;
    {
      const int swz = (lr & 7) << 4;
      pf0 = *reinterpret_cast<const bf16x8*>(pbase + ((lr * 128 + lg * 16)      ^ swz));
      pf1 = *reinterpret_cast<const bf16x8*>(pbase + ((lr * 128 + 64 + lg * 16) ^ swz));
    }
    #pragma unroll
    for (int d = 0; d < 16; d++) {
      const unsigned short* vp = vtb + (size_t)(d * 16 + lr) * SEQ + kv0 + lg * 8;
      bf16x8 v0 = *reinterpret_cast<const bf16x8*>(vp);
      bf16x8 v1 = *reinterpret_cast<const bf16x8*>(vp + 32);
      o[d] = __builtin_amdgcn_mfma_f32_16x16x32_bf16(pf0, v0, o[d], 0, 0, 0);
      o[d] = __builtin_amdgcn_mfma_f32_16x16x32_bf16(pf1, v1, o[d], 0, 0, 0);
    }
  }

  // ---- write partials (unnormalized)
  const size_t obase = (size_t)t * (64 * 256) + (size_t)(wave * 16 + lg * 4) * 256 + lr;
  #pragma unroll
  for (int d = 0; d < 16; d++)
    #pragma unroll
    for (int r = 0; r < 4; r++)
      pO[obase + r * 256 + d * 16] = o[d][r];
  if (lr == 0) {
    #pragma unroll
    for (int r = 0; r < 4; r++) {
      const int lrw = wave * 16 + lg * 4 + r;
      ml[(size_t)t * 128 + lrw * 2]     = m_run[r];
      ml[(size_t)t * 128 + lrw * 2 + 1] = l_run[r];
    }
  }
}

// ---- merge partials: out[row][c] = sum_i O_i exp(m_i - M) / sum_i l_i exp(m_i - M)
__global__ __launch_bounds__(256) void merge_kernel(
    const float* __restrict__ pO, const float* __restrict__ ml,
    float* __restrict__ out)
{
  const int tid = threadIdx.x;
  const int row = blockIdx.x * 32 + (tid >> 3);
  const int c0  = (tid & 7) * 32;
  const int q = row >> 6;
  const int g = q >> 4;
  const int n = g + 1;                              // chunks for this qtile
  const int base = q + 8 * g * (g - 1) + (q - 16 * g) * g;  // start task id
  const int lrow = row & 63;

  float M = -3.0e38f;
  for (int i = 0; i < n; i++)
    M = fmaxf(M, ml[(size_t)(base + i) * 128 + lrow * 2]);

  float L = 0.f;
  float4 a0 = {0,0,0,0}, a1 = {0,0,0,0}, a2 = {0,0,0,0}, a3 = {0,0,0,0};
  float4 a4 = {0,0,0,0}, a5 = {0,0,0,0}, a6 = {0,0,0,0}, a7 = {0,0,0,0};
  for (int i = 0; i < n; i++) {
    const float mi = ml[(size_t)(base + i) * 128 + lrow * 2];
    const float li = ml[(size_t)(base + i) * 128 + lrow * 2 + 1];
    const float fi = __expf(mi - M);
    L += li * fi;
    const float4* src = reinterpret_cast<const float4*>(
        &pO[(size_t)(base + i) * (64 * 256) + (size_t)lrow * 256 + c0]);
    float4 v;
    v = src[0]; a0.x += v.x*fi; a0.y += v.y*fi; a0.z += v.z*fi; a0.w += v.w*fi;
    v = src[1]; a1.x += v.x*fi; a1.y += v.y*fi; a1.z += v.z*fi; a1.w += v.w*fi;
    v = src[2]; a2.x += v.x*fi; a2.y += v.y*fi; a2.z += v.z*fi; a2.w += v.w*fi;
    v = src[3]; a3.x += v.x*fi; a3.y += v.y*fi; a3.z += v.z*fi; a3.w += v.w*fi;
    v = src[4]; a4.x += v.x*fi; a4.y += v.y*fi; a4.z += v.z*fi; a4.w += v.w*fi;
    v = src[5]; a5.x += v.x*fi; a5.y += v.y*fi; a5.z += v.z*fi; a5.w += v.w*fi;
    v = src[6]; a6.x += v.x*fi; a6.y += v.y*fi; a6.z += v.z*fi; a6.w += v.w*fi;
    v = src[7]; a7.x += v.x*fi; a7.y += v.y*fi; a7.z += v.z*fi; a7.w += v.w*fi;
  }
  const float inv = 1.f / L;
  float4* dst = reinterpret_cast<float4*>(&out[(size_t)row * 256 + c0]);
  a0.x*=inv; a0.y*=inv; a0.z*=inv; a0.w*=inv; dst[0]=a0;
  a1.x*=inv; a1.y*=inv; a1.z*=inv; a1.w*=inv; dst[1]=a1;
  a2.x*=inv; a2.y*=inv; a2.z*=inv; a2.w*=inv; dst[2]=a2;
  a3.x*=inv; a3.y*=inv; a3.z*=inv; a3.w*=inv; dst[3]=a3;
  a4.x*=inv; a4.y*=inv; a4.z*=inv; a4.w*=inv; dst[4]=a4;
  a5.x*=inv; a5.y*=inv; a5.z*=inv; a5.w*=inv; dst[5]=a5;
  a6.x*=inv; a6.y*=inv; a6.z*=inv; a6.w*=inv; dst[6]=a6;
  a7.x*=inv; a7.y*=inv; a7.z*=inv; a7.w*=inv; dst[7]=a7;
}

extern "C" void kernel_launch(void* const* d_in, const int* in_sizes, int n_in,
                              void* d_out, int out_size, void* d_ws, size_t ws_size,
                              hipStream_t stream)
{
  const float* x  = (const float*)d_in[0];
  const float* Wq = (const float*)d_in[1];
  const float* Wk = (const float*)d_in[2];
  const float* Wv = (const float*)d_in[3];

  char* ws = (char*)d_ws;
  unsigned short* qb  = (unsigned short*)ws;                       // 4 MB
  unsigned short* kb  = (unsigned short*)(ws + (size_t)4  * 1024 * 1024);
  unsigned short* vtb = (unsigned short*)(ws + (size_t)8  * 1024 * 1024);
  float*          ml  = (float*)         (ws + (size_t)12 * 1024 * 1024);   // 288 KB
  float*          pO  = (float*)         (ws + (size_t)12 * 1024 * 1024 + 512 * 1024); // ~36 MB

  proj_kernel<<<dim3(64, 2, 3), 256, 0, stream>>>(x, Wq, Wk, Wv, qb, kb, vtb);
  attn_kernel<<<dim3(NTASKS), 256, 0, stream>>>(qb, kb, vtb, pO, ml);
  merge_kernel<<<dim3(SEQ / 32), 256, 0, stream>>>(pO, ml, (float*)d_out);
}